// Round 1
// baseline (204.818 us; speedup 1.0000x reference)
//
#include <hip/hip_runtime.h>

#define TT 512
#define BB 512
#define NN 64
#define LN2F 0.69314718055994530942f

typedef _Float16 half8_t __attribute__((ext_vector_type(8)));
typedef float    f32x4   __attribute__((ext_vector_type(4)));

union AFrag { int u[4]; half8_t h; };

__device__ __forceinline__ float wave_sum(float v) {
    #pragma unroll
    for (int off = 32; off > 0; off >>= 1)
        v += __shfl_xor(v, off, 64);
    return v;
}

__device__ __forceinline__ int wave_sum_i(int v) {
    #pragma unroll
    for (int off = 32; off > 0; off >>= 1)
        v += __shfl_xor(v, off, 64);
    return v;
}

__device__ __forceinline__ float bcast_lane(float v, int lane) {
    return __uint_as_float(__builtin_amdgcn_readlane(__float_as_uint(v), lane));
}

// async global->LDS DMA, 4 bytes/lane: LDS dest = uniform base + lane*4.
__device__ __forceinline__ void async4(const float* g, float* l) {
    __builtin_amdgcn_global_load_lds(
        (const __attribute__((address_space(1))) unsigned int*)g,
        (__attribute__((address_space(3))) unsigned int*)l,
        4, 0, 0);
}

// Zero the scalar output (harness poisons d_out with 0xAA before every launch).
__global__ void zero_kernel(float* __restrict__ out) {
    if (threadIdx.x == 0 && blockIdx.x == 0) out[0] = 0.0f;
}

// r13: eliminate the per-step ds_bpermute from the u-chain by swapping MFMA
// operand roles. A now holds the (column-permuted) transition matrix, B holds
// u replicated over its 16 columns. With the output-state permutation
//   sigma(g,m) = 32*(g>>1) + 8*(m>>2) + 2*(m&3) + (g&1)
// lane L (group q=L>>4) receives, in acc[g][r], exactly the 16 u' values
// (states {8q..8q+7} u {32+8q..32+8q+7}) that its OWN next-step B-fragment
// needs: Bf[kh].reg[r] = pkrtz(acc[2kh][r]*w, acc[2kh+1][r]*w). Chain is now
// MFMA x2 -> mul -> ldexp -> pkrtz -> MFMA (no cross-lane op).
// The 16 per-lane w=exp(emit) values are produced OFF-chain: each lane exps
// one owned state sL, bounces through LDS wbuf, steps read 4x ds_read_b128
// (broadcast within 16-lane groups, conflict-free). w for block j+1 is made
// at the END of block j (its DMA landed during the 8 steps).
// Rescale scheme unchanged: e from lane0's pre-w y (state 0) +4 guard,
// e_sum += e+2 restores the 0.25=2^-2 folded into the A entries.
__global__ __launch_bounds__(64) void crf_fwd_kernel(
    const float* __restrict__ emit,
    const float* __restrict__ trans,
    const float* __restrict__ strans,
    const float* __restrict__ etrans,
    const int*   __restrict__ target,
    const void*  __restrict__ maskp,
    float* __restrict__ out)
{
    const int b = blockIdx.x;
    const int k = threadIdx.x;

    __shared__ float sem[2][8][NN];    // 4 KB emit ring: [half][slot][state]
    __shared__ float wbuf[2][8][NN];   // 4 KB w=exp(emit) double buffer
    __shared__ float ebuf[NN];         // etrans staged for the final LSE

    const int*           mi32 = (const int*)maskp;
    const unsigned char* mi8  = (const unsigned char*)maskp;
    // mask[0,:] is all-true (lengths >= 1): byte encoding -> word0 == 0x01010101.
    const bool bytemode = (mi32[0] == 0x01010101);

    // len[b] = sum_t mask[t,b] (mask monotone per column) — one-time cost.
    int cnt = 0;
    #pragma unroll
    for (int i = 0; i < TT / 64; ++i) {
        const size_t tb = (size_t)(i * 64 + k) * BB + b;
        cnt += bytemode ? (mi8[tb] != 0) : (mi32[tb] != 0);
    }
    const int len = wave_sum_i(cnt);   // wave-uniform

    const int q   = k >> 4;
    const int m15 = k & 15;
    // owned state for the w bounce: group q's lanes own {8q..8q+7, 32+8q..+7}
    const int sL  = ((k & 8) << 2) | (q << 3) | (k & 7);

    ebuf[k] = etrans[k];

    const float* ecol = emit + (size_t)b * NN + k;   // row stride BB*NN

    // Prologue: DMA rows 1..8 into half 0 (rows 1..8 always exist: TT=512).
    #pragma unroll
    for (int s = 0; s < 8; ++s)
        async4(ecol + (size_t)(1 + s) * BB * NN, &sem[0][s][0]);

    // A fragments: Af[g][kh] lane L element j = A[m=L&15][k32=8q+j]
    //   = 0.25*exp(trans[(32kh+8q+j)][sigma(g, L&15)]).
    half8_t Af[4][2];
    #pragma unroll
    for (int g = 0; g < 4; ++g) {
        const int nsg = 32 * (g >> 1) + 8 * (m15 >> 2) + 2 * (m15 & 3) + (g & 1);
        #pragma unroll
        for (int kh = 0; kh < 2; ++kh) {
            AFrag af;
            #pragma unroll
            for (int jp = 0; jp < 4; ++jp) {
                const int krow = 32 * kh + 8 * q + 2 * jp;
                const float e0 = 0.25f * __expf(trans[(krow + 0) * NN + nsg]);
                const float e1 = 0.25f * __expf(trans[(krow + 1) * NN + nsg]);
                af.u[jp] = __builtin_bit_cast(int, __builtin_amdgcn_cvt_pkrtz(e0, e1));
            }
            Af[g][kh] = af.h;
        }
    }

    const f32x4 zero4 = {0.f, 0.f, 0.f, 0.f};

    // t = 0: u = exp(alpha0 - m0), redistributed via a one-time LDS bounce
    // (wbuf[1][0] is free until the end of block 0).
    const float a0 = emit[(size_t)b * NN + sL] + strans[sL];
    const float m0 = bcast_lane(a0, 0);
    wbuf[1][0][sL] = __expf(a0 - m0);
    asm volatile("" ::: "memory");
    f32x4 uL0 = *(const f32x4*)&wbuf[1][0][8 * q + 0];
    f32x4 uL1 = *(const f32x4*)&wbuf[1][0][8 * q + 4];
    f32x4 uH0 = *(const f32x4*)&wbuf[1][0][32 + 8 * q + 0];
    f32x4 uH1 = *(const f32x4*)&wbuf[1][0][32 + 8 * q + 4];

    half8_t Bf0, Bf1;
    auto mkB = [&]() {
        AFrag b0, b1;
        b0.u[0] = __builtin_bit_cast(int, __builtin_amdgcn_cvt_pkrtz(uL0[0], uL0[1]));
        b0.u[1] = __builtin_bit_cast(int, __builtin_amdgcn_cvt_pkrtz(uL0[2], uL0[3]));
        b0.u[2] = __builtin_bit_cast(int, __builtin_amdgcn_cvt_pkrtz(uL1[0], uL1[1]));
        b0.u[3] = __builtin_bit_cast(int, __builtin_amdgcn_cvt_pkrtz(uL1[2], uL1[3]));
        b1.u[0] = __builtin_bit_cast(int, __builtin_amdgcn_cvt_pkrtz(uH0[0], uH0[1]));
        b1.u[1] = __builtin_bit_cast(int, __builtin_amdgcn_cvt_pkrtz(uH0[2], uH0[3]));
        b1.u[2] = __builtin_bit_cast(int, __builtin_amdgcn_cvt_pkrtz(uH1[0], uH1[1]));
        b1.u[3] = __builtin_bit_cast(int, __builtin_amdgcn_cvt_pkrtz(uH1[2], uH1[3]));
        Bf0 = b0.h; Bf1 = b1.h;
    };
    mkB();

    int e_sum = 0;

    // One exp-domain step: 8 MFMAs, then 16 lane-local mul+ldexp, repack.
    auto do_step = [&](int wb_, int s) {
        const f32x4 wl0 = *(const f32x4*)&wbuf[wb_][s][8 * q + 0];
        const f32x4 wl1 = *(const f32x4*)&wbuf[wb_][s][8 * q + 4];
        const f32x4 wh0 = *(const f32x4*)&wbuf[wb_][s][32 + 8 * q + 0];
        const f32x4 wh1 = *(const f32x4*)&wbuf[wb_][s][32 + 8 * q + 4];

        const f32x4 aA0 = __builtin_amdgcn_mfma_f32_16x16x32_f16(Af[0][0], Bf0, zero4, 0, 0, 0);
        const f32x4 aA1 = __builtin_amdgcn_mfma_f32_16x16x32_f16(Af[1][0], Bf0, zero4, 0, 0, 0);
        const f32x4 aA2 = __builtin_amdgcn_mfma_f32_16x16x32_f16(Af[2][0], Bf0, zero4, 0, 0, 0);
        const f32x4 aA3 = __builtin_amdgcn_mfma_f32_16x16x32_f16(Af[3][0], Bf0, zero4, 0, 0, 0);
        const f32x4 ac0 = __builtin_amdgcn_mfma_f32_16x16x32_f16(Af[0][1], Bf1, aA0, 0, 0, 0);
        const f32x4 ac1 = __builtin_amdgcn_mfma_f32_16x16x32_f16(Af[1][1], Bf1, aA1, 0, 0, 0);
        const f32x4 ac2 = __builtin_amdgcn_mfma_f32_16x16x32_f16(Af[2][1], Bf1, aA2, 0, 0, 0);
        const f32x4 ac3 = __builtin_amdgcn_mfma_f32_16x16x32_f16(Af[3][1], Bf1, aA3, 0, 0, 0);

        // e from lane0's PRE-w y_0 (+4 guard) — readfirstlane/SALU overlaps the muls.
        const int e = (int)((__builtin_amdgcn_readfirstlane(__float_as_uint(ac0[0])) >> 23) & 0xff) - 127 + 4;

        // acc[g][r] = y at state 32*(g>>1) + 8q + 2r + (g&1)
        uL0[0] = ldexpf(ac0[0] * wl0[0], -e);
        uL0[1] = ldexpf(ac1[0] * wl0[1], -e);
        uL0[2] = ldexpf(ac0[1] * wl0[2], -e);
        uL0[3] = ldexpf(ac1[1] * wl0[3], -e);
        uL1[0] = ldexpf(ac0[2] * wl1[0], -e);
        uL1[1] = ldexpf(ac1[2] * wl1[1], -e);
        uL1[2] = ldexpf(ac0[3] * wl1[2], -e);
        uL1[3] = ldexpf(ac1[3] * wl1[3], -e);
        uH0[0] = ldexpf(ac2[0] * wh0[0], -e);
        uH0[1] = ldexpf(ac3[0] * wh0[1], -e);
        uH0[2] = ldexpf(ac2[1] * wh0[2], -e);
        uH0[3] = ldexpf(ac3[1] * wh0[3], -e);
        uH1[0] = ldexpf(ac2[2] * wh1[0], -e);
        uH1[1] = ldexpf(ac3[2] * wh1[1], -e);
        uH1[2] = ldexpf(ac2[3] * wh1[2], -e);
        uH1[3] = ldexpf(ac3[3] * wh1[3], -e);

        mkB();
        e_sum += e + 2;   // +2 restores the 0.25=2^-2 folded into A (exact)
    };

    // Produce a block's w rows (off the u-chain). Per-lane: 1 ds_read + exp +
    // 1 ds_write of the owned state. DS pipe is in-order per wave; the asm
    // fence only pins compiler ordering (zero instructions).
    auto produce_w = [&](int srchalf, int dstwb) {
        #pragma unroll
        for (int s = 0; s < 8; ++s)
            wbuf[dstwb][s][sL] = __expf(sem[srchalf][s][sL]);
        asm volatile("" ::: "memory");
    };

    produce_w(0, 0);   // block 0 (vmcnt-waits on the prologue DMAs, once)

    int t = 1, half = 0, wb = 0;
    for (; t + 8 <= len; t += 8) {
        // issue next block's DMAs (clamped at TT-1; overshoot never consumed)
        #pragma unroll
        for (int s = 0; s < 8; ++s) {
            const int tf = (t + 8 + s < TT) ? (t + 8 + s) : (TT - 1);
            async4(ecol + (size_t)tf * BB * NN, &sem[half ^ 1][s][0]);
        }
        do_step(wb, 0); do_step(wb, 1); do_step(wb, 2); do_step(wb, 3);
        do_step(wb, 4); do_step(wb, 5); do_step(wb, 6); do_step(wb, 7);
        // next block's w: its DMA landed during the 8 steps above
        produce_w(half ^ 1, wb ^ 1);
        half ^= 1; wb ^= 1;
    }

    // Remainder (< 8 steps): rows t..len-1 in sem[half], w already in wbuf[wb].
    for (int s = 0; t < len; ++t, ++s)
        do_step(wb, s);

    // logZ_b = m0 + ln2*e_sum + logsumexp over the 16 per-lane states
    // (values replicated across each 16-lane group: reduce via xor16 + xor32).
    const f32x4 el0 = *(const f32x4*)&ebuf[8 * q + 0];
    const f32x4 el1 = *(const f32x4*)&ebuf[8 * q + 4];
    const f32x4 eh0 = *(const f32x4*)&ebuf[32 + 8 * q + 0];
    const f32x4 eh1 = *(const f32x4*)&ebuf[32 + 8 * q + 4];

    f32x4 l0, l1, h0, h1;
    #pragma unroll
    for (int i = 0; i < 4; ++i) {
        l0[i] = __logf(uL0[i]) + el0[i];
        l1[i] = __logf(uL1[i]) + el1[i];
        h0[i] = __logf(uH0[i]) + eh0[i];
        h1[i] = __logf(uH1[i]) + eh1[i];
    }
    float mx = l0[0];
    #pragma unroll
    for (int i = 0; i < 4; ++i) {
        mx = fmaxf(mx, l0[i]); mx = fmaxf(mx, l1[i]);
        mx = fmaxf(mx, h0[i]); mx = fmaxf(mx, h1[i]);
    }
    mx = fmaxf(mx, __shfl_xor(mx, 16, 64));
    mx = fmaxf(mx, __shfl_xor(mx, 32, 64));
    float sm = 0.f;
    #pragma unroll
    for (int i = 0; i < 4; ++i) {
        sm += __expf(l0[i] - mx); sm += __expf(l1[i] - mx);
        sm += __expf(h0[i] - mx); sm += __expf(h1[i] - mx);
    }
    sm += __shfl_xor(sm, 16, 64);
    sm += __shfl_xor(sm, 32, 64);
    const float logZ_b = m0 + LN2F * (float)e_sum + mx + __logf(sm);

    // ---- fused gold score for batch b: lane k covers t = 64*i + k ----
    int tvals[TT / 64];
    #pragma unroll
    for (int i = 0; i < TT / 64; ++i)
        tvals[i] = target[(size_t)(64 * i + k) * BB + b];

    float g = 0.f;
    int prev_last = 0;
    #pragma unroll
    for (int i = 0; i < TT / 64; ++i) {
        const int tt = 64 * i + k;
        const int tgt = tvals[i];
        int tprev = __shfl_up(tvals[i], 1, 64);
        if (k == 0) tprev = prev_last;                       // carry across i
        prev_last = __builtin_amdgcn_readlane(tvals[i], 63);
        if (tt < len) {
            float v = emit[((size_t)tt * BB + b) * NN + tgt];
            v += (tt == 0) ? strans[tgt] : trans[tprev * NN + tgt];
            if (tt == len - 1) v += etrans[tgt];
            g += v;
        }
    }
    g = wave_sum(g);

    if (k == 0) atomicAdd(out, logZ_b - g);
}

extern "C" void kernel_launch(void* const* d_in, const int* in_sizes, int n_in,
                              void* d_out, int out_size, void* d_ws, size_t ws_size,
                              hipStream_t stream) {
    const float* emit   = (const float*)d_in[0];
    const float* trans  = (const float*)d_in[1];
    const float* strans = (const float*)d_in[2];
    const float* etrans = (const float*)d_in[3];
    const int*   target = (const int*)d_in[4];
    const void*  mask   = d_in[5];
    float* out = (float*)d_out;

    hipLaunchKernelGGL(zero_kernel, dim3(1), dim3(64), 0, stream, out);
    hipLaunchKernelGGL(crf_fwd_kernel, dim3(BB), dim3(64), 0, stream,
                       emit, trans, strans, etrans, target, mask, out);
}

// Round 2
// 197.527 us; speedup vs baseline: 1.0369x; 1.0369x over previous
//
#include <hip/hip_runtime.h>

#define TT 512
#define BB 512
#define NN 64
#define LN2F 0.69314718055994530942f
#define CGUARD 7   // normalization target: probe state ~= 2^-CGUARD after scaling

typedef _Float16 half8_t __attribute__((ext_vector_type(8)));
typedef float    f32x4   __attribute__((ext_vector_type(4)));

union AFrag { int u[4]; half8_t h; };

__device__ __forceinline__ float wave_sum(float v) {
    #pragma unroll
    for (int off = 32; off > 0; off >>= 1)
        v += __shfl_xor(v, off, 64);
    return v;
}

__device__ __forceinline__ int wave_sum_i(int v) {
    #pragma unroll
    for (int off = 32; off > 0; off >>= 1)
        v += __shfl_xor(v, off, 64);
    return v;
}

__device__ __forceinline__ float bcast_lane(float v, int lane) {
    return __uint_as_float(__builtin_amdgcn_readlane(__float_as_uint(v), lane));
}

// async global->LDS DMA, 4 bytes/lane: LDS dest = uniform base + lane*4.
__device__ __forceinline__ void async4(const float* g, float* l) {
    __builtin_amdgcn_global_load_lds(
        (const __attribute__((address_space(1))) unsigned int*)g,
        (__attribute__((address_space(3))) unsigned int*)l,
        4, 0, 0);
}

// Zero the scalar output (harness poisons d_out with 0xAA before every launch).
__global__ void zero_kernel(float* __restrict__ out) {
    if (threadIdx.x == 0 && blockIdx.x == 0) out[0] = 0.0f;
}

// r14 = r13's operand-swapped MFMA structure with the tail taken OFF the chain.
//  - Chain per step: MFMA -> MFMA (C-chained, throughput-free per m119) ->
//    16 v_mul (u = y*wt) -> 8 pkrtz -> Bf -> next MFMA.  ~L+35 cyc.
//  - Normalization is DELAYED: d_t is probed from step t-1's stored u~ (f16
//    exponent bits of Bf pairs for states {0,1,32,33} via readfirstlane+SALU),
//    and folded into wt = ldexp(w_raw, -d) OFF-chain while MFMAs run.
//    Accounting stays exact: e_sum += d+2 per step (+2 = the 0.25 in A).
//    Feedback is history-free (log u~_{t+1} = growth - CGUARD), and pkrtz
//    rounds toward zero so overflow saturates at 65504 instead of inf.
//  - w_raw for step s+1 is prefetched into registers at the TOP of step s;
//    produce_w runs one full block ahead (DMA two blocks ahead), so no LDS
//    latency ever lands on the u-chain.
__global__ __launch_bounds__(64) void crf_fwd_kernel(
    const float* __restrict__ emit,
    const float* __restrict__ trans,
    const float* __restrict__ strans,
    const float* __restrict__ etrans,
    const int*   __restrict__ target,
    const void*  __restrict__ maskp,
    float* __restrict__ out)
{
    const int b = blockIdx.x;
    const int k = threadIdx.x;

    __shared__ float sem[2][8][NN];    // emit ring, 2 blocks deep
    __shared__ float wbuf[2][8][NN];   // w = exp(emit), produced 1 block ahead
    __shared__ float ibuf[NN];         // t=0 redistribution bounce
    __shared__ float ebuf[NN];         // etrans staged for the final LSE

    const int*           mi32 = (const int*)maskp;
    const unsigned char* mi8  = (const unsigned char*)maskp;
    const bool bytemode = (mi32[0] == 0x01010101);

    // len[b] = sum_t mask[t,b]
    int cnt = 0;
    #pragma unroll
    for (int i = 0; i < TT / 64; ++i) {
        const size_t tb = (size_t)(i * 64 + k) * BB + b;
        cnt += bytemode ? (mi8[tb] != 0) : (mi32[tb] != 0);
    }
    const int len = wave_sum_i(cnt);   // wave-uniform

    const int q   = k >> 4;
    const int m15 = k & 15;
    // owned state for the producer bounce (any bijection works)
    const int sL  = ((k & 8) << 2) | (q << 3) | (k & 7);

    ebuf[k] = etrans[k];

    const float* ecol = emit + (size_t)b * NN + k;   // row stride BB*NN

    // Prologue DMAs: block0 (rows 1..8) -> sem[0], block1 (rows 9..16) -> sem[1].
    #pragma unroll
    for (int s = 0; s < 8; ++s)
        async4(ecol + (size_t)(1 + s) * BB * NN, &sem[0][s][0]);
    #pragma unroll
    for (int s = 0; s < 8; ++s)
        async4(ecol + (size_t)(9 + s) * BB * NN, &sem[1][s][0]);

    // A fragments (identical to r13, correctness-verified):
    // Af[g][kh] lane elem j = 0.25*exp(trans[(32kh+8q+j)][sigma(g, m15)]).
    half8_t Af[4][2];
    #pragma unroll
    for (int g = 0; g < 4; ++g) {
        const int nsg = 32 * (g >> 1) + 8 * (m15 >> 2) + 2 * (m15 & 3) + (g & 1);
        #pragma unroll
        for (int kh = 0; kh < 2; ++kh) {
            AFrag af;
            #pragma unroll
            for (int jp = 0; jp < 4; ++jp) {
                const int krow = 32 * kh + 8 * q + 2 * jp;
                const float e0 = 0.25f * __expf(trans[(krow + 0) * NN + nsg]);
                const float e1 = 0.25f * __expf(trans[(krow + 1) * NN + nsg]);
                af.u[jp] = __builtin_bit_cast(int, __builtin_amdgcn_cvt_pkrtz(e0, e1));
            }
            Af[g][kh] = af.h;
        }
    }

    const f32x4 zero4 = {0.f, 0.f, 0.f, 0.f};

    // t = 0: u~0 = exp(alpha0 - m0), redistributed once through ibuf.
    const float a0 = emit[(size_t)b * NN + sL] + strans[sL];
    const float m0 = bcast_lane(a0, 0);   // sL(0) == 0
    ibuf[sL] = __expf(a0 - m0);
    asm volatile("" ::: "memory");

    float uL[8], uH[8];   // lane's 16 u~ values: states 8q+j and 32+8q+j
    {
        const f32x4 i0 = *(const f32x4*)&ibuf[8 * q + 0];
        const f32x4 i1 = *(const f32x4*)&ibuf[8 * q + 4];
        const f32x4 i2 = *(const f32x4*)&ibuf[32 + 8 * q + 0];
        const f32x4 i3 = *(const f32x4*)&ibuf[32 + 8 * q + 4];
        #pragma unroll
        for (int j = 0; j < 4; ++j) {
            uL[j] = i0[j]; uL[4 + j] = i1[j];
            uH[j] = i2[j]; uH[4 + j] = i3[j];
        }
    }

    AFrag Bf0, Bf1;
    #pragma unroll
    for (int r = 0; r < 4; ++r) {
        Bf0.u[r] = __builtin_bit_cast(int, __builtin_amdgcn_cvt_pkrtz(uL[2 * r], uL[2 * r + 1]));
        Bf1.u[r] = __builtin_bit_cast(int, __builtin_amdgcn_cvt_pkrtz(uH[2 * r], uH[2 * r + 1]));
    }

    // d-probe: max f16 exponent over states {0,1,32,33} (lane0's first pairs).
    auto probe = [&]() -> int {
        const int p0 = __builtin_amdgcn_readfirstlane(Bf0.u[0]);
        const int p1 = __builtin_amdgcn_readfirstlane(Bf1.u[0]);
        int mA = p0 & 0x7fff, mB = (p0 >> 16) & 0x7fff;
        int mC = p1 & 0x7fff, mD = (p1 >> 16) & 0x7fff;
        int mm = mA > mB ? mA : mB;
        int mn = mC > mD ? mC : mD;
        if (mn > mm) mm = mn;
        return (mm >> 10) - 15 + CGUARD;
    };

    // Produce block0's w (waits on the prologue DMAs once).
    #pragma unroll
    for (int s = 0; s < 8; ++s)
        wbuf[0][s][sL] = __expf(sem[0][s][sL]);
    asm volatile("" ::: "memory");

    int d = probe();    // scale to apply at step t=1 (already folded into wt)
    int e_sum = 0;

    // wt = w_raw * 2^-d for the upcoming step (16 regs, off-chain maintained)
    float wt[16];
    {
        const f32x4 n0 = *(const f32x4*)&wbuf[0][0][8 * q + 0];
        const f32x4 n1 = *(const f32x4*)&wbuf[0][0][8 * q + 4];
        const f32x4 n2 = *(const f32x4*)&wbuf[0][0][32 + 8 * q + 0];
        const f32x4 n3 = *(const f32x4*)&wbuf[0][0][32 + 8 * q + 4];
        #pragma unroll
        for (int j = 0; j < 4; ++j) {
            wt[j]      = ldexpf(n0[j], -d);
            wt[4 + j]  = ldexpf(n1[j], -d);
            wt[8 + j]  = ldexpf(n2[j], -d);
            wt[12 + j] = ldexpf(n3[j], -d);
        }
    }

    // One step. wnext points at the NEXT step's raw-w row (prefetched here).
    auto do_step = [&](const float* wnext) {
        // (off-chain) prefetch next step's raw w
        const f32x4 n0 = *(const f32x4*)&wnext[8 * q + 0];
        const f32x4 n1 = *(const f32x4*)&wnext[8 * q + 4];
        const f32x4 n2 = *(const f32x4*)&wnext[32 + 8 * q + 0];
        const f32x4 n3 = *(const f32x4*)&wnext[32 + 8 * q + 4];

        // (chain) y = u~ * 0.25E : 4 output groups, K-halves C-chained
        const f32x4 aA0 = __builtin_amdgcn_mfma_f32_16x16x32_f16(Af[0][0], Bf0.h, zero4, 0, 0, 0);
        const f32x4 aA1 = __builtin_amdgcn_mfma_f32_16x16x32_f16(Af[1][0], Bf0.h, zero4, 0, 0, 0);
        const f32x4 aA2 = __builtin_amdgcn_mfma_f32_16x16x32_f16(Af[2][0], Bf0.h, zero4, 0, 0, 0);
        const f32x4 aA3 = __builtin_amdgcn_mfma_f32_16x16x32_f16(Af[3][0], Bf0.h, zero4, 0, 0, 0);
        const f32x4 ac0 = __builtin_amdgcn_mfma_f32_16x16x32_f16(Af[0][1], Bf1.h, aA0, 0, 0, 0);
        const f32x4 ac1 = __builtin_amdgcn_mfma_f32_16x16x32_f16(Af[1][1], Bf1.h, aA1, 0, 0, 0);
        const f32x4 ac2 = __builtin_amdgcn_mfma_f32_16x16x32_f16(Af[2][1], Bf1.h, aA2, 0, 0, 0);
        const f32x4 ac3 = __builtin_amdgcn_mfma_f32_16x16x32_f16(Af[3][1], Bf1.h, aA3, 0, 0, 0);

        // (chain) u~ = y * wt ; repack to f16 pairs.  acc_g[r] is the y at
        // state 32*(g>>1) + 8q + 2r + (g&1).  pkrtz saturates on overflow.
        #pragma unroll
        for (int r = 0; r < 4; ++r) {
            uL[2 * r]     = ac0[r] * wt[2 * r];
            uL[2 * r + 1] = ac1[r] * wt[2 * r + 1];
            uH[2 * r]     = ac2[r] * wt[8 + 2 * r];
            uH[2 * r + 1] = ac3[r] * wt[8 + 2 * r + 1];
        }
        #pragma unroll
        for (int r = 0; r < 4; ++r) {
            Bf0.u[r] = __builtin_bit_cast(int, __builtin_amdgcn_cvt_pkrtz(uL[2 * r], uL[2 * r + 1]));
            Bf1.u[r] = __builtin_bit_cast(int, __builtin_amdgcn_cvt_pkrtz(uH[2 * r], uH[2 * r + 1]));
        }

        // (off-chain) accounting + next scale + next wt
        e_sum += d + 2;
        d = probe();
        #pragma unroll
        for (int j = 0; j < 4; ++j) {
            wt[j]      = ldexpf(n0[j], -d);
            wt[4 + j]  = ldexpf(n1[j], -d);
            wt[8 + j]  = ldexpf(n2[j], -d);
            wt[12 + j] = ldexpf(n3[j], -d);
        }
    };

    int t = 1, p = 0;
    // Invariants at iter top (block j, p=j&1): sem[p^1] holds block j+1's rows
    // (DMA'd >=1 block ago); wbuf[p] holds block j's w (produced last iter).
    for (; t + 8 <= len; t += 8) {
        // produce block j+1's w
        #pragma unroll
        for (int s = 0; s < 8; ++s)
            wbuf[p ^ 1][s][sL] = __expf(sem[p ^ 1][s][sL]);
        asm volatile("" ::: "memory");
        // DMA block j+2 -> sem[p] (clamped; overshoot rows never consumed)
        #pragma unroll
        for (int s = 0; s < 8; ++s) {
            const int tf = (t + 16 + s < TT) ? (t + 16 + s) : (TT - 1);
            async4(ecol + (size_t)tf * BB * NN, &sem[p][s][0]);
        }
        do_step(&wbuf[p][1][0]);
        do_step(&wbuf[p][2][0]);
        do_step(&wbuf[p][3][0]);
        do_step(&wbuf[p][4][0]);
        do_step(&wbuf[p][5][0]);
        do_step(&wbuf[p][6][0]);
        do_step(&wbuf[p][7][0]);
        do_step(&wbuf[p ^ 1][0][0]);   // prefetch next block's slot 0
        p ^= 1;
    }

    // Remainder (<8 steps): w already in wbuf[p].
    for (int s = 0; t < len; ++t, ++s)
        do_step(&wbuf[p][s + 1][0]);

    // logZ_b = m0 + ln2*e_sum + logsumexp over the 16 per-lane states
    // (replicated across each 16-lane group: reduce via xor16 + xor32).
    const f32x4 el0 = *(const f32x4*)&ebuf[8 * q + 0];
    const f32x4 el1 = *(const f32x4*)&ebuf[8 * q + 4];
    const f32x4 eh0 = *(const f32x4*)&ebuf[32 + 8 * q + 0];
    const f32x4 eh1 = *(const f32x4*)&ebuf[32 + 8 * q + 4];

    float l[16];
    #pragma unroll
    for (int j = 0; j < 4; ++j) {
        l[j]      = __logf(uL[j])     + el0[j];
        l[4 + j]  = __logf(uL[4 + j]) + el1[j];
        l[8 + j]  = __logf(uH[j])     + eh0[j];
        l[12 + j] = __logf(uH[4 + j]) + eh1[j];
    }
    float mx = l[0];
    #pragma unroll
    for (int j = 1; j < 16; ++j) mx = fmaxf(mx, l[j]);
    mx = fmaxf(mx, __shfl_xor(mx, 16, 64));
    mx = fmaxf(mx, __shfl_xor(mx, 32, 64));
    float sm = 0.f;
    #pragma unroll
    for (int j = 0; j < 16; ++j) sm += __expf(l[j] - mx);
    sm += __shfl_xor(sm, 16, 64);
    sm += __shfl_xor(sm, 32, 64);
    const float logZ_b = m0 + LN2F * (float)e_sum + mx + __logf(sm);

    // ---- fused gold score for batch b: lane k covers t = 64*i + k ----
    int tvals[TT / 64];
    #pragma unroll
    for (int i = 0; i < TT / 64; ++i)
        tvals[i] = target[(size_t)(64 * i + k) * BB + b];

    float g = 0.f;
    int prev_last = 0;
    #pragma unroll
    for (int i = 0; i < TT / 64; ++i) {
        const int tt = 64 * i + k;
        const int tgt = tvals[i];
        int tprev = __shfl_up(tvals[i], 1, 64);
        if (k == 0) tprev = prev_last;                       // carry across i
        prev_last = __builtin_amdgcn_readlane(tvals[i], 63);
        if (tt < len) {
            float v = emit[((size_t)tt * BB + b) * NN + tgt];
            v += (tt == 0) ? strans[tgt] : trans[tprev * NN + tgt];
            if (tt == len - 1) v += etrans[tgt];
            g += v;
        }
    }
    g = wave_sum(g);

    if (k == 0) atomicAdd(out, logZ_b - g);
}

extern "C" void kernel_launch(void* const* d_in, const int* in_sizes, int n_in,
                              void* d_out, int out_size, void* d_ws, size_t ws_size,
                              hipStream_t stream) {
    const float* emit   = (const float*)d_in[0];
    const float* trans  = (const float*)d_in[1];
    const float* strans = (const float*)d_in[2];
    const float* etrans = (const float*)d_in[3];
    const int*   target = (const int*)d_in[4];
    const void*  mask   = d_in[5];
    float* out = (float*)d_out;

    hipLaunchKernelGGL(zero_kernel, dim3(1), dim3(64), 0, stream, out);
    hipLaunchKernelGGL(crf_fwd_kernel, dim3(BB), dim3(64), 0, stream,
                       emit, trans, strans, etrans, target, mask, out);
}